// Round 8
// baseline (8357.670 us; speedup 1.0000x reference)
//
#include <hip/hip_runtime.h>

typedef unsigned int u32;
#define LN_EPS 1e-5f

// ---------- helpers ----------
__device__ __forceinline__ float wave_sum(float v){
  #pragma unroll
  for (int o = 32; o > 0; o >>= 1) v += __shfl_xor(v, o, 64);
  return v;
}
// mish(x) = x*tanh(softplus(x)) = x*(1 - 2/(u+2)), u = e^x(e^x+2)
__device__ __forceinline__ float mishf(float v){
  float t = __expf(v);
  float u = t*t + 2.f*t;
  return v * (1.f - 2.f/(u + 2.f));
}

// LDS layout (floats) — total 11,184 f = 44,736 B  (3 blocks/CU)
#define OFF_ATT   0        // 64x68 = 4352 (att/P; pool partials after GEMM)
#define OFF_WT    4352     // 16x257 = 4112 (Wt; compute_att aliases sB/qB)
#define OFF_X16   8464     // 256  (x-side LN slice, [l][4])
#define OFF_AS    8720     // 256  (attention-out slice, [l][4])
#define OFF_OT    8976     // 4x68 = 272 (other-side LN slice, transposed [u][l])
#define OFF_GAM   9248     // 256
#define OFF_BET   9504     // 256
#define OFF_C1S   9760     // 64
#define OFF_C2S   9824     // 64
#define OFF_C1Q   9888     // 64
#define OFF_C2Q   9952     // 64
#define OFF_SMX   10016    // 64
#define OFF_SMI   10080    // 64
#define OFF_CAT   10144    // 1024
#define OFF_RED   11168    // 8
#define OFF_STAT  11176    // 2
#define OFF_MRED  11178    // 4
#define LDS_TOT   11184

__global__ __launch_bounds__(256, 3) void k_pair8(
    const float* __restrict__ sup, const float* __restrict__ qry,
    const float* __restrict__ lng, const float* __restrict__ lnb,
    const float* __restrict__ ln2g, const float* __restrict__ ln2b,
    const float* __restrict__ Wg,  const float* __restrict__ pbias,
    const float* __restrict__ W1,  const float* __restrict__ b1,
    const float* __restrict__ W2,  const float* __restrict__ b2,
    const float* __restrict__ W3,  const float* __restrict__ b3,
    float* __restrict__ logits)
{
  __shared__ float SM[LDS_TOT];
  float* att = SM + OFF_ATT;
  float* Wt  = SM + OFF_WT;
  float* sB  = SM + OFF_WT;          // alias: compute_att staging
  float* qB  = SM + OFF_WT + 1024;   // alias
  float* x16 = SM + OFF_X16;
  float* as16= SM + OFF_AS;
  float* oT  = SM + OFF_OT;
  float* gam = SM + OFF_GAM;
  float* bet = SM + OFF_BET;
  float* c1s = SM + OFF_C1S;
  float* c2s = SM + OFF_C2S;
  float* c1q = SM + OFF_C1Q;
  float* c2q = SM + OFF_C2Q;
  float* smx = SM + OFF_SMX;
  float* smi = SM + OFF_SMI;
  float* cat = SM + OFF_CAT;
  float* red = SM + OFF_RED;
  float* stat= SM + OFF_STAT;
  float* mred= SM + OFF_MRED;

  const int m = blockIdx.x;              // (b*50+nq)*10 + n
  const int b = m / 500, rr = m % 500, nq = rr / 10, n_ = rr % 10;
  const float* sbase = sup + (size_t)(b*10 + n_) * 16384;
  const float* qbase = qry + (size_t)(b*50 + nq) * 16384;

  const int t = threadIdx.x;             // 256
  const int w = t >> 6, lane = t & 63;

  // ---- Phase A: LN params + per-row coefficients c1 = rstd, c2 = -mu*rstd ----
  gam[t] = lng[t];
  bet[t] = lnb[t];
  for (int r = w; r < 64; r += 4){
    float4 x = *(const float4*)(sbase + r*256 + lane*4);
    float s  = wave_sum(x.x + x.y + x.z + x.w);
    float sq = wave_sum(x.x*x.x + x.y*x.y + x.z*x.z + x.w*x.w);
    if (lane == 0){
      float mu = s*(1.f/256.f);
      float rstd = 1.f/sqrtf(sq*(1.f/256.f) - mu*mu + LN_EPS);
      c1s[r] = rstd; c2s[r] = -mu*rstd;
    }
  }
  for (int r = w; r < 64; r += 4){
    float4 x = *(const float4*)(qbase + r*256 + lane*4);
    float s  = wave_sum(x.x + x.y + x.z + x.w);
    float sq = wave_sum(x.x*x.x + x.y*x.y + x.z*x.z + x.w*x.w);
    if (lane == 0){
      float mu = s*(1.f/256.f);
      float rstd = 1.f/sqrtf(sq*(1.f/256.f) - mu*mu + LN_EPS);
      c1q[r] = rstd; c2q[r] = -mu*rstd;
    }
  }
  __syncthreads();

  // ---- attention scores att[l][k] = sln_l . qln_k (stride 68) ----
  auto compute_att = [&](){
    float aa[4][4];
    #pragma unroll
    for (int i = 0; i < 4; i++)
      #pragma unroll
      for (int j = 0; j < 4; j++) aa[i][j] = 0.f;
    const int ty = t >> 4, tx = t & 15;
    for (int sl = 0; sl < 16; sl++){
      __syncthreads();
      const int dbase = sl*16;
      #pragma unroll
      for (int r = 0; r < 4; r++){
        int idx = t + 256*r;
        int l = idx >> 4, u = idx & 15;
        float g = gam[dbase+u], bb = bet[dbase+u];
        sB[l*16+u] = fmaf(fmaf(sbase[l*256 + dbase+u], c1s[l], c2s[l]), g, bb);
        qB[l*16+u] = fmaf(fmaf(qbase[l*256 + dbase+u], c1q[l], c2q[l]), g, bb);
      }
      __syncthreads();
      #pragma unroll
      for (int u4 = 0; u4 < 4; u4++){
        int uu = (u4 + tx) & 3;
        float4 sv[4], qv[4];
        #pragma unroll
        for (int i = 0; i < 4; i++) sv[i] = *(const float4*)&sB[(ty*4+i)*16 + uu*4];
        #pragma unroll
        for (int j = 0; j < 4; j++) qv[j] = *(const float4*)&qB[(tx*4+j)*16 + uu*4];
        #pragma unroll
        for (int i = 0; i < 4; i++)
          #pragma unroll
          for (int j = 0; j < 4; j++)
            aa[i][j] += sv[i].x*qv[j].x + sv[i].y*qv[j].y + sv[i].z*qv[j].z + sv[i].w*qv[j].w;
      }
    }
    __syncthreads();
    #pragma unroll
    for (int i = 0; i < 4; i++)
      #pragma unroll
      for (int j = 0; j < 4; j++)
        att[(ty*4+i)*68 + tx*4+j] = aa[i][j];
    __syncthreads();
  };

  // ---- softmax: rowwise in-place; colwise writes TRANSPOSED (P[k][l]) ----
  auto softmax_row = [&](){
    if (t < 64){
      float mxv = -1e30f, sm = 0.f;
      for (int k = 0; k < 64; k++) mxv = fmaxf(mxv, att[t*68 + k]);
      for (int k = 0; k < 64; k++) sm += __expf(att[t*68 + k] - mxv);
      smx[t] = mxv; smi[t] = 1.f/sm;
    }
    __syncthreads();
    #pragma unroll
    for (int r = 0; r < 16; r++){
      int idx = t + 256*r;
      int l = idx >> 6, k = idx & 63;
      att[l*68 + k] = __expf(att[l*68 + k] - smx[l]) * smi[l];
    }
    __syncthreads();
  };
  auto softmax_col_T = [&](){
    if (t < 64){
      float mxv = -1e30f, sm = 0.f;
      for (int l = 0; l < 64; l++) mxv = fmaxf(mxv, att[l*68 + t]);
      for (int l = 0; l < 64; l++) sm += __expf(att[l*68 + t] - mxv);
      smx[t] = mxv; smi[t] = 1.f/sm;
    }
    __syncthreads();
    float v[16];
    #pragma unroll
    for (int r = 0; r < 16; r++){
      int idx = t + 256*r;
      int l = idx >> 6, k = idx & 63;
      v[r] = __expf(att[l*68 + k] - smx[k]) * smi[k];
    }
    __syncthreads();
    #pragma unroll
    for (int r = 0; r < 16; r++){
      int idx = t + 256*r;
      int l = idx >> 6, k = idx & 63;
      att[k*68 + l] = v[r];              // transposed: P[out_row][sum_idx]
    }
    __syncthreads();
  };

  // ---- proj+mish+pool+LN2 for one side -> cat[cat_off..+512) ----
  // P in att: [out_row][sum_idx] (stride 68). Thread owns n = lane*4..+3;
  // wave w owns l-quarter 16w..16w+15. acc[16][4].
  auto proj_side = [&](const float* xb, const float* c1x, const float* c2x,
                       const float* ob, const float* c1o, const float* c2o,
                       int cat_off){
    float acc[16][4];
    #pragma unroll
    for (int i = 0; i < 16; i++)
      #pragma unroll
      for (int j = 0; j < 4; j++) acc[i][j] = 0.f;

    const int xrow = t >> 2, xcol = t & 3;

    for (int kt = 0; kt < 64; kt++){
      __syncthreads();
      const int dbase = kt*4;
      #pragma unroll
      for (int r = 0; r < 4; r++){       // Wt[(c*4+dd)*257 + n] = W[n][c*256+dbase+dd]
        int idx = t + 256*r;
        int n = idx >> 2, c = idx & 3;
        float4 wv = *(const float4*)(Wg + n*1024 + c*256 + dbase);
        Wt[(c*4+0)*257 + n] = wv.x;
        Wt[(c*4+1)*257 + n] = wv.y;
        Wt[(c*4+2)*257 + n] = wv.z;
        Wt[(c*4+3)*257 + n] = wv.w;
      }
      {
        float g = gam[dbase+xcol], bb = bet[dbase+xcol];
        x16[t] = fmaf(fmaf(xb[xrow*256 + dbase + xcol], c1x[xrow], c2x[xrow]), g, bb);
        oT[xcol*68 + xrow] = fmaf(fmaf(ob[xrow*256 + dbase + xcol], c1o[xrow], c2o[xrow]), g, bb);
      }
      __syncthreads();
      {                                  // as16[row][u] = sum_j P[row][j]*oln[j][u]
        const float* pr = &att[xrow*68];
        const float* orow = &oT[xcol*68];
        float s = 0.f;
        #pragma unroll
        for (int j4 = 0; j4 < 16; j4++){
          float4 pv = *(const float4*)(pr + j4*4);
          float4 ov = *(const float4*)(orow + j4*4);
          s += pv.x*ov.x + pv.y*ov.y + pv.z*ov.z + pv.w*ov.w;
        }
        as16[t] = s;
      }
      __syncthreads();
      float wreg[64];
      #pragma unroll
      for (int kk = 0; kk < 16; kk++){
        float4 wv = *(const float4*)&Wt[kk*257 + lane*4];
        wreg[kk*4+0] = wv.x; wreg[kk*4+1] = wv.y;
        wreg[kk*4+2] = wv.z; wreg[kk*4+3] = wv.w;
      }
      #pragma unroll
      for (int ll = 0; ll < 16; ll++){
        int l = (w << 4) + ll;
        float4 xv = *(const float4*)&x16[l*4];   // broadcast within wave
        float4 av = *(const float4*)&as16[l*4];  // broadcast within wave
        float e[16];
        e[0]=xv.x; e[1]=xv.y; e[2]=xv.z; e[3]=xv.w;
        e[4]=av.x; e[5]=av.y; e[6]=av.z; e[7]=av.w;
        e[8]=fabsf(xv.x-av.x); e[9]=fabsf(xv.y-av.y);
        e[10]=fabsf(xv.z-av.z); e[11]=fabsf(xv.w-av.w);
        e[12]=xv.x*av.x; e[13]=xv.y*av.y; e[14]=xv.z*av.z; e[15]=xv.w*av.w;
        #pragma unroll
        for (int kk = 0; kk < 16; kk++){
          acc[ll][0] = fmaf(e[kk], wreg[kk*4+0], acc[ll][0]);
          acc[ll][1] = fmaf(e[kk], wreg[kk*4+1], acc[ll][1]);
          acc[ll][2] = fmaf(e[kk], wreg[kk*4+2], acc[ll][2]);
          acc[ll][3] = fmaf(e[kk], wreg[kk*4+3], acc[ll][3]);
        }
      }
    }
    __syncthreads();                     // P dead -> att region becomes pool partials

    float* pmax = att;                   // [4][256]
    float* psum = att + 1024;            // [4][256]
    {
      float4 pb = *(const float4*)&pbias[lane*4];
      float pbv[4] = {pb.x, pb.y, pb.z, pb.w};
      float mx[4] = {-1e30f,-1e30f,-1e30f,-1e30f};
      float sm[4] = {0.f,0.f,0.f,0.f};
      #pragma unroll
      for (int ll = 0; ll < 16; ll++)
        #pragma unroll
        for (int j = 0; j < 4; j++){
          float v = mishf(acc[ll][j] + pbv[j]);
          mx[j] = fmaxf(mx[j], v);
          sm[j] += v;
        }
      float4 m4; m4.x=mx[0]; m4.y=mx[1]; m4.z=mx[2]; m4.w=mx[3];
      float4 s4; s4.x=sm[0]; s4.y=sm[1]; s4.z=sm[2]; s4.w=sm[3];
      *(float4*)&pmax[w*256 + lane*4] = m4;
      *(float4*)&psum[w*256 + lane*4] = s4;
    }
    __syncthreads();
    float mm = -1e30f, ss = 0.f;
    #pragma unroll
    for (int ww = 0; ww < 4; ww++){
      mm = fmaxf(mm, pmax[ww*256 + t]);
      ss += psum[ww*256 + t];
    }
    float v1 = mm, v2 = ss * (1.f/64.f);
    float p1 = wave_sum(v1 + v2);
    float p2 = wave_sum(v1*v1 + v2*v2);
    if (lane == 0){ red[w] = p1; red[4+w] = p2; }
    __syncthreads();
    if (t == 0){
      float s1 = red[0]+red[1]+red[2]+red[3];
      float s2 = red[4]+red[5]+red[6]+red[7];
      float mu  = s1 * (1.f/512.f);
      float var = s2 * (1.f/512.f) - mu*mu;
      stat[0] = mu; stat[1] = 1.f/sqrtf(var + LN_EPS);
    }
    __syncthreads();
    float mu = stat[0], rstd = stat[1];
    cat[cat_off + t]       = (v1 - mu)*rstd*ln2g[t]       + ln2b[t];
    cat[cat_off + 256 + t] = (v2 - mu)*rstd*ln2g[256 + t] + ln2b[256 + t];
    __syncthreads();
  };

  // ===== side S: P = rowSoftmax(att); x = sln, other = qln =====
  compute_att();
  softmax_row();
  proj_side(sbase, c1s, c2s, qbase, c1q, c2q, 512);

  // ===== side Q: P = colSoftmax(att)^T; x = qln, other = sln =====
  compute_att();
  softmax_col_T();
  proj_side(qbase, c1q, c2q, sbase, c1s, c2s, 0);

  // ===== MLP =====
  {
    const float* wr = W1 + t*1024;
    float acc = 0.f;
    #pragma unroll 4
    for (int i = 0; i < 256; i++){
      float4 u4 = *(const float4*)(wr + i*4);
      const float* cp = &cat[i*4];
      acc += cp[0]*u4.x + cp[1]*u4.y + cp[2]*u4.z + cp[3]*u4.w;
    }
    float hv = mishf(acc + b1[t]);
    float contrib = wave_sum(hv * W2[t]);
    if (lane == 0) mred[w] = contrib;
  }
  __syncthreads();
  if (t == 0){
    float hh = mred[0] + mred[1] + mred[2] + mred[3] + b2[0];
    logits[m] = mishf(hh)*W3[0] + b3[0];
  }
}

// ---------- finalize (fp32 output) ----------
__global__ void k_final8(const float* __restrict__ logits, float* __restrict__ out){
  int t = threadIdx.x;                   // 128
  if (t < 100){
    float v[10];
    float mn = 1e30f;
    #pragma unroll
    for (int j = 0; j < 10; j++){ v[j] = logits[t*10 + j]; mn = fminf(mn, v[j]); }
    float best = -1e30f; int bi = 0;
    #pragma unroll
    for (int j = 0; j < 10; j++){ if (v[j] > best){ best = v[j]; bi = j; } }
    #pragma unroll
    for (int j = 0; j < 10; j++) out[t*11 + j] = v[j];
    out[t*11 + 10] = mn - 1.f;
    out[1100 + t] = (float)bi;
  }
}

// ---------- launcher ----------
extern "C" void kernel_launch(void* const* d_in, const int* in_sizes, int n_in,
                              void* d_out, int out_size, void* d_ws, size_t ws_size,
                              hipStream_t stream){
  (void)in_sizes; (void)n_in; (void)out_size; (void)ws_size;
  const float* support = (const float*)d_in[0];
  const float* query   = (const float*)d_in[1];
  const float* ln_g    = (const float*)d_in[2];
  const float* ln_b    = (const float*)d_in[3];
  const float* ln2_g   = (const float*)d_in[4];
  const float* ln2_b   = (const float*)d_in[5];
  const float* proj_W  = (const float*)d_in[6];
  const float* proj_b  = (const float*)d_in[7];
  const float* W1      = (const float*)d_in[8];
  const float* b1      = (const float*)d_in[9];
  const float* W2      = (const float*)d_in[10];
  const float* b2      = (const float*)d_in[11];
  const float* W3      = (const float*)d_in[12];
  const float* b3      = (const float*)d_in[13];

  float* logits = (float*)d_ws;          // 4 KB workspace

  k_pair8<<<dim3(1000), dim3(256), 0, stream>>>(support, query, ln_g, ln_b,
                                                ln2_g, ln2_b, proj_W, proj_b,
                                                W1, b1, W2, b2, W3, b3, logits);
  k_final8<<<dim3(1), dim3(128), 0, stream>>>(logits, (float*)d_out);
}

// Round 9
// 1739.266 us; speedup vs baseline: 4.8053x; 4.8053x over previous
//
#include <hip/hip_runtime.h>

typedef unsigned int u32;
#define LN_EPS 1e-5f

// ---------- helpers ----------
__device__ __forceinline__ float wave_sum(float v){
  #pragma unroll
  for (int o = 32; o > 0; o >>= 1) v += __shfl_xor(v, o, 64);
  return v;
}
// mish(x) = x*tanh(softplus(x)) = x*(1 - 2/(u+2)), u = e^x(e^x+2)
__device__ __forceinline__ float mishf(float v){
  float t = __expf(v);
  float u = t*t + 2.f*t;
  return v * (1.f - 2.f/(u + 2.f));
}

// LDS layout (floats) — total 11,184 f = 44,736 B  (2 blocks/CU at VGPR~200)
#define OFF_ATT   0        // 64x68 = 4352 (att/P; pool partials after GEMM)
#define OFF_WT    4352     // 16x257 = 4112 (Wt; compute_att aliases sB/qB)
#define OFF_X16   8464     // 256  (x-side LN slice, [l][4])
#define OFF_AS    8720     // 256  (attention-out slice, [l][4])
#define OFF_OT    8976     // 4x68 = 272 (other-side LN slice, transposed [u][l])
#define OFF_GAM   9248     // 256
#define OFF_BET   9504     // 256
#define OFF_C1S   9760     // 64
#define OFF_C2S   9824     // 64
#define OFF_C1Q   9888     // 64
#define OFF_C2Q   9952     // 64
#define OFF_SMX   10016    // 64
#define OFF_SMI   10080    // 64
#define OFF_CAT   10144    // 1024
#define OFF_RED   11168    // 8
#define OFF_STAT  11176    // 2
#define OFF_MRED  11178    // 4
#define LDS_TOT   11184

// launch_bounds(256,2): VGPR cap 256 — the r8 (256,3) variant clamped to 84 VGPRs
// and spilled acc+wreg to scratch (20 GB HBM writes, 3.2x regression).
__global__ __launch_bounds__(256, 2) void k_pair9(
    const float* __restrict__ sup, const float* __restrict__ qry,
    const float* __restrict__ lng, const float* __restrict__ lnb,
    const float* __restrict__ ln2g, const float* __restrict__ ln2b,
    const float* __restrict__ Wg,  const float* __restrict__ pbias,
    const float* __restrict__ W1,  const float* __restrict__ b1,
    const float* __restrict__ W2,  const float* __restrict__ b2,
    const float* __restrict__ W3,  const float* __restrict__ b3,
    float* __restrict__ logits)
{
  __shared__ float SM[LDS_TOT];
  float* att = SM + OFF_ATT;
  float* Wt  = SM + OFF_WT;
  float* sB  = SM + OFF_WT;          // alias: compute_att staging
  float* qB  = SM + OFF_WT + 1024;   // alias
  float* x16 = SM + OFF_X16;
  float* as16= SM + OFF_AS;
  float* oT  = SM + OFF_OT;
  float* gam = SM + OFF_GAM;
  float* bet = SM + OFF_BET;
  float* c1s = SM + OFF_C1S;
  float* c2s = SM + OFF_C2S;
  float* c1q = SM + OFF_C1Q;
  float* c2q = SM + OFF_C2Q;
  float* smx = SM + OFF_SMX;
  float* smi = SM + OFF_SMI;
  float* cat = SM + OFF_CAT;
  float* red = SM + OFF_RED;
  float* stat= SM + OFF_STAT;
  float* mred= SM + OFF_MRED;

  const int m = blockIdx.x;              // (b*50+nq)*10 + n
  const int b = m / 500, rr = m % 500, nq = rr / 10, n_ = rr % 10;
  const float* sbase = sup + (size_t)(b*10 + n_) * 16384;
  const float* qbase = qry + (size_t)(b*50 + nq) * 16384;

  const int t = threadIdx.x;             // 256
  const int w = t >> 6, lane = t & 63;

  // ---- Phase A: LN params + per-row coefficients c1 = rstd, c2 = -mu*rstd ----
  gam[t] = lng[t];
  bet[t] = lnb[t];
  for (int r = w; r < 64; r += 4){
    float4 x = *(const float4*)(sbase + r*256 + lane*4);
    float s  = wave_sum(x.x + x.y + x.z + x.w);
    float sq = wave_sum(x.x*x.x + x.y*x.y + x.z*x.z + x.w*x.w);
    if (lane == 0){
      float mu = s*(1.f/256.f);
      float rstd = 1.f/sqrtf(sq*(1.f/256.f) - mu*mu + LN_EPS);
      c1s[r] = rstd; c2s[r] = -mu*rstd;
    }
  }
  for (int r = w; r < 64; r += 4){
    float4 x = *(const float4*)(qbase + r*256 + lane*4);
    float s  = wave_sum(x.x + x.y + x.z + x.w);
    float sq = wave_sum(x.x*x.x + x.y*x.y + x.z*x.z + x.w*x.w);
    if (lane == 0){
      float mu = s*(1.f/256.f);
      float rstd = 1.f/sqrtf(sq*(1.f/256.f) - mu*mu + LN_EPS);
      c1q[r] = rstd; c2q[r] = -mu*rstd;
    }
  }
  __syncthreads();

  // ---- attention scores att[l][k] = sln_l . qln_k (stride 68) ----
  auto compute_att = [&](){
    float aa[4][4];
    #pragma unroll
    for (int i = 0; i < 4; i++)
      #pragma unroll
      for (int j = 0; j < 4; j++) aa[i][j] = 0.f;
    const int ty = t >> 4, tx = t & 15;
    for (int sl = 0; sl < 16; sl++){
      __syncthreads();
      const int dbase = sl*16;
      #pragma unroll
      for (int r = 0; r < 4; r++){
        int idx = t + 256*r;
        int l = idx >> 4, u = idx & 15;
        float g = gam[dbase+u], bb = bet[dbase+u];
        sB[l*16+u] = fmaf(fmaf(sbase[l*256 + dbase+u], c1s[l], c2s[l]), g, bb);
        qB[l*16+u] = fmaf(fmaf(qbase[l*256 + dbase+u], c1q[l], c2q[l]), g, bb);
      }
      __syncthreads();
      #pragma unroll
      for (int u4 = 0; u4 < 4; u4++){
        int uu = (u4 + tx) & 3;
        float4 sv[4], qv[4];
        #pragma unroll
        for (int i = 0; i < 4; i++) sv[i] = *(const float4*)&sB[(ty*4+i)*16 + uu*4];
        #pragma unroll
        for (int j = 0; j < 4; j++) qv[j] = *(const float4*)&qB[(tx*4+j)*16 + uu*4];
        #pragma unroll
        for (int i = 0; i < 4; i++)
          #pragma unroll
          for (int j = 0; j < 4; j++)
            aa[i][j] += sv[i].x*qv[j].x + sv[i].y*qv[j].y + sv[i].z*qv[j].z + sv[i].w*qv[j].w;
      }
    }
    __syncthreads();
    #pragma unroll
    for (int i = 0; i < 4; i++)
      #pragma unroll
      for (int j = 0; j < 4; j++)
        att[(ty*4+i)*68 + tx*4+j] = aa[i][j];
    __syncthreads();
  };

  // ---- softmax: rowwise in-place; colwise writes TRANSPOSED (P[k][l]) ----
  auto softmax_row = [&](){
    if (t < 64){
      float mxv = -1e30f, sm = 0.f;
      for (int k = 0; k < 64; k++) mxv = fmaxf(mxv, att[t*68 + k]);
      for (int k = 0; k < 64; k++) sm += __expf(att[t*68 + k] - mxv);
      smx[t] = mxv; smi[t] = 1.f/sm;
    }
    __syncthreads();
    #pragma unroll
    for (int r = 0; r < 16; r++){
      int idx = t + 256*r;
      int l = idx >> 6, k = idx & 63;
      att[l*68 + k] = __expf(att[l*68 + k] - smx[l]) * smi[l];
    }
    __syncthreads();
  };
  auto softmax_col_T = [&](){
    if (t < 64){
      float mxv = -1e30f, sm = 0.f;
      for (int l = 0; l < 64; l++) mxv = fmaxf(mxv, att[l*68 + t]);
      for (int l = 0; l < 64; l++) sm += __expf(att[l*68 + t] - mxv);
      smx[t] = mxv; smi[t] = 1.f/sm;
    }
    __syncthreads();
    float v[16];
    #pragma unroll
    for (int r = 0; r < 16; r++){
      int idx = t + 256*r;
      int l = idx >> 6, k = idx & 63;
      v[r] = __expf(att[l*68 + k] - smx[k]) * smi[k];
    }
    __syncthreads();
    #pragma unroll
    for (int r = 0; r < 16; r++){
      int idx = t + 256*r;
      int l = idx >> 6, k = idx & 63;
      att[k*68 + l] = v[r];              // transposed: P[out_row][sum_idx]
    }
    __syncthreads();
  };

  // ---- proj+mish+pool+LN2 for one side -> cat[cat_off..+512) ----
  auto proj_side = [&](const float* xb, const float* c1x, const float* c2x,
                       const float* ob, const float* c1o, const float* c2o,
                       int cat_off){
    float acc[16][4];
    #pragma unroll
    for (int i = 0; i < 16; i++)
      #pragma unroll
      for (int j = 0; j < 4; j++) acc[i][j] = 0.f;

    const int xrow = t >> 2, xcol = t & 3;

    for (int kt = 0; kt < 64; kt++){
      __syncthreads();
      const int dbase = kt*4;
      #pragma unroll
      for (int r = 0; r < 4; r++){       // Wt[(c*4+dd)*257 + n] = W[n][c*256+dbase+dd]
        int idx = t + 256*r;
        int n = idx >> 2, c = idx & 3;
        float4 wv = *(const float4*)(Wg + n*1024 + c*256 + dbase);
        Wt[(c*4+0)*257 + n] = wv.x;
        Wt[(c*4+1)*257 + n] = wv.y;
        Wt[(c*4+2)*257 + n] = wv.z;
        Wt[(c*4+3)*257 + n] = wv.w;
      }
      {
        float g = gam[dbase+xcol], bb = bet[dbase+xcol];
        x16[t] = fmaf(fmaf(xb[xrow*256 + dbase + xcol], c1x[xrow], c2x[xrow]), g, bb);
        oT[xcol*68 + xrow] = fmaf(fmaf(ob[xrow*256 + dbase + xcol], c1o[xrow], c2o[xrow]), g, bb);
      }
      __syncthreads();
      {                                  // as16[row][u] = sum_j P[row][j]*oln[j][u]
        const float* pr = &att[xrow*68];
        const float* orow = &oT[xcol*68];
        float s = 0.f;
        #pragma unroll
        for (int j4 = 0; j4 < 16; j4++){
          float4 pv = *(const float4*)(pr + j4*4);
          float4 ov = *(const float4*)(orow + j4*4);
          s += pv.x*ov.x + pv.y*ov.y + pv.z*ov.z + pv.w*ov.w;
        }
        as16[t] = s;
      }
      __syncthreads();
      float wreg[64];
      #pragma unroll
      for (int kk = 0; kk < 16; kk++){
        float4 wv = *(const float4*)&Wt[kk*257 + lane*4];
        wreg[kk*4+0] = wv.x; wreg[kk*4+1] = wv.y;
        wreg[kk*4+2] = wv.z; wreg[kk*4+3] = wv.w;
      }
      #pragma unroll
      for (int ll = 0; ll < 16; ll++){
        int l = (w << 4) + ll;
        float4 xv = *(const float4*)&x16[l*4];   // broadcast within wave
        float4 av = *(const float4*)&as16[l*4];  // broadcast within wave
        float e[16];
        e[0]=xv.x; e[1]=xv.y; e[2]=xv.z; e[3]=xv.w;
        e[4]=av.x; e[5]=av.y; e[6]=av.z; e[7]=av.w;
        e[8]=fabsf(xv.x-av.x); e[9]=fabsf(xv.y-av.y);
        e[10]=fabsf(xv.z-av.z); e[11]=fabsf(xv.w-av.w);
        e[12]=xv.x*av.x; e[13]=xv.y*av.y; e[14]=xv.z*av.z; e[15]=xv.w*av.w;
        #pragma unroll
        for (int kk = 0; kk < 16; kk++){
          acc[ll][0] = fmaf(e[kk], wreg[kk*4+0], acc[ll][0]);
          acc[ll][1] = fmaf(e[kk], wreg[kk*4+1], acc[ll][1]);
          acc[ll][2] = fmaf(e[kk], wreg[kk*4+2], acc[ll][2]);
          acc[ll][3] = fmaf(e[kk], wreg[kk*4+3], acc[ll][3]);
        }
      }
    }
    __syncthreads();                     // P dead -> att region becomes pool partials

    float* pmax = att;                   // [4][256]
    float* psum = att + 1024;            // [4][256]
    {
      float4 pb = *(const float4*)&pbias[lane*4];
      float pbv[4] = {pb.x, pb.y, pb.z, pb.w};
      float mx[4] = {-1e30f,-1e30f,-1e30f,-1e30f};
      float sm[4] = {0.f,0.f,0.f,0.f};
      #pragma unroll
      for (int ll = 0; ll < 16; ll++)
        #pragma unroll
        for (int j = 0; j < 4; j++){
          float v = mishf(acc[ll][j] + pbv[j]);
          mx[j] = fmaxf(mx[j], v);
          sm[j] += v;
        }
      float4 m4; m4.x=mx[0]; m4.y=mx[1]; m4.z=mx[2]; m4.w=mx[3];
      float4 s4; s4.x=sm[0]; s4.y=sm[1]; s4.z=sm[2]; s4.w=sm[3];
      *(float4*)&pmax[w*256 + lane*4] = m4;
      *(float4*)&psum[w*256 + lane*4] = s4;
    }
    __syncthreads();
    float mm = -1e30f, ss = 0.f;
    #pragma unroll
    for (int ww = 0; ww < 4; ww++){
      mm = fmaxf(mm, pmax[ww*256 + t]);
      ss += psum[ww*256 + t];
    }
    float v1 = mm, v2 = ss * (1.f/64.f);
    float p1 = wave_sum(v1 + v2);
    float p2 = wave_sum(v1*v1 + v2*v2);
    if (lane == 0){ red[w] = p1; red[4+w] = p2; }
    __syncthreads();
    if (t == 0){
      float s1 = red[0]+red[1]+red[2]+red[3];
      float s2 = red[4]+red[5]+red[6]+red[7];
      float mu  = s1 * (1.f/512.f);
      float var = s2 * (1.f/512.f) - mu*mu;
      stat[0] = mu; stat[1] = 1.f/sqrtf(var + LN_EPS);
    }
    __syncthreads();
    float mu = stat[0], rstd = stat[1];
    cat[cat_off + t]       = (v1 - mu)*rstd*ln2g[t]       + ln2b[t];
    cat[cat_off + 256 + t] = (v2 - mu)*rstd*ln2g[256 + t] + ln2b[256 + t];
    __syncthreads();
  };

  // ===== side S: P = rowSoftmax(att); x = sln, other = qln =====
  compute_att();
  softmax_row();
  proj_side(sbase, c1s, c2s, qbase, c1q, c2q, 512);

  // ===== side Q: P = colSoftmax(att)^T; x = qln, other = sln =====
  compute_att();
  softmax_col_T();
  proj_side(qbase, c1q, c2q, sbase, c1s, c2s, 0);

  // ===== MLP =====
  {
    const float* wr = W1 + t*1024;
    float acc = 0.f;
    #pragma unroll 4
    for (int i = 0; i < 256; i++){
      float4 u4 = *(const float4*)(wr + i*4);
      const float* cp = &cat[i*4];
      acc += cp[0]*u4.x + cp[1]*u4.y + cp[2]*u4.z + cp[3]*u4.w;
    }
    float hv = mishf(acc + b1[t]);
    float contrib = wave_sum(hv * W2[t]);
    if (lane == 0) mred[w] = contrib;
  }
  __syncthreads();
  if (t == 0){
    float hh = mred[0] + mred[1] + mred[2] + mred[3] + b2[0];
    logits[m] = mishf(hh)*W3[0] + b3[0];
  }
}

// ---------- finalize (fp32 output) ----------
__global__ void k_final9(const float* __restrict__ logits, float* __restrict__ out){
  int t = threadIdx.x;                   // 128
  if (t < 100){
    float v[10];
    float mn = 1e30f;
    #pragma unroll
    for (int j = 0; j < 10; j++){ v[j] = logits[t*10 + j]; mn = fminf(mn, v[j]); }
    float best = -1e30f; int bi = 0;
    #pragma unroll
    for (int j = 0; j < 10; j++){ if (v[j] > best){ best = v[j]; bi = j; } }
    #pragma unroll
    for (int j = 0; j < 10; j++) out[t*11 + j] = v[j];
    out[t*11 + 10] = mn - 1.f;
    out[1100 + t] = (float)bi;
  }
}

// ---------- launcher ----------
extern "C" void kernel_launch(void* const* d_in, const int* in_sizes, int n_in,
                              void* d_out, int out_size, void* d_ws, size_t ws_size,
                              hipStream_t stream){
  (void)in_sizes; (void)n_in; (void)out_size; (void)ws_size;
  const float* support = (const float*)d_in[0];
  const float* query   = (const float*)d_in[1];
  const float* ln_g    = (const float*)d_in[2];
  const float* ln_b    = (const float*)d_in[3];
  const float* ln2_g   = (const float*)d_in[4];
  const float* ln2_b   = (const float*)d_in[5];
  const float* proj_W  = (const float*)d_in[6];
  const float* proj_b  = (const float*)d_in[7];
  const float* W1      = (const float*)d_in[8];
  const float* b1      = (const float*)d_in[9];
  const float* W2      = (const float*)d_in[10];
  const float* b2      = (const float*)d_in[11];
  const float* W3      = (const float*)d_in[12];
  const float* b3      = (const float*)d_in[13];

  float* logits = (float*)d_ws;          // 4 KB workspace

  k_pair9<<<dim3(1000), dim3(256), 0, stream>>>(support, query, ln_g, ln_b,
                                                ln2_g, ln2_b, proj_W, proj_b,
                                                W1, b1, W2, b2, W3, b3, logits);
  k_final9<<<dim3(1), dim3(128), 0, stream>>>(logits, (float*)d_out);
}